// Round 12
// baseline (891.139 us; speedup 1.0000x reference)
//
#include <hip/hip_runtime.h>

// Fused SpikingDenseLayer: B=256, T=100, F=K=1024, U=1024.
// One block = one (batch b, 128-wide u-tile), 256 threads.
// v13 = v5 (best verified, 630 us) + dependency-stall removal:
//  * REVISED MODEL (v10 vs v11 falsified the LDS-pipe-bound theory: a 4-way
//    W-read conflict worth ~330 us of pipe time cost only ~30 us -> LDS pipe
//    has slack; broadcast-aliased reads are cheap). All rounds are bound by
//    the iter-top ds_read -> FMA lgkmcnt stall (~120+ cyc per 448-cyc iter)
//    with barrier-lockstep keeping waves correlated. VALUBusy tracks wall
//    everywhere (72%->630, 61%->700, 59%->740).
//  * Fix 1: A+W staging double-buffered (2 x 14.6 KB) -> 64 barriers (was
//    128), vmcnt drain covered by a full compute phase.
//  * Fix 2: register ping-pong prefetch of LDS operands (v8's pattern --
//    valid here because LDS latency ~120 cyc < half-iter FMA cover ~224 cyc;
//    v8 failed covering ~900 cyc HBM latency). Preload (kk,kk+1); per 4-k:
//    load n(kk+2,3) -> FMA c -> load c(kk+4,5) -> FMA n. FMA blocks consume
//    only preloaded regs.
//  * acc 56 + A c/n 28 + W c/n 32 ~= 120-135 VGPR. NO launch_bounds cap
//    (v3/v4 lesson: cap ~= 256/arg forces spill). Spill tripwire:
//    WRITE_SIZE must stay exactly 103424 KB.
//  * staging maps verified since v2 (A [100][16], W [16][128], linear,
//    conflict counter 0); tail rows 96..99 wave-uniform on wave 0.
// FMA order per output element identical to v5 (k-ascending, same per-row
// expression order) -> currents bitwise identical; LIF scan verbatim v5.

#define UN 128              // u-columns per block
#define BK 16               // k-slice staged per buffer
#define CS 132              // Cs row stride in floats (128 + 4)
#define CHUNK 50            // t-rows per scan chunk
#define TMAX 100

__device__ __forceinline__ void gload_lds16(const float* g, float* l) {
    __builtin_amdgcn_global_load_lds(
        (const __attribute__((address_space(1))) void*)g,
        (__attribute__((address_space(3))) void*)l,
        16, 0, 0);
}

__global__ __launch_bounds__(256) void fused_snn(
    const float* __restrict__ x,     // [B,T,F]
    const float* __restrict__ W,     // [F,U]
    const float* __restrict__ bias,  // [U]
    float* __restrict__ spikes,      // [B,T,U]
    float* __restrict__ counts,      // [B,U]
    int B, int T, int F, int U)
{
    // GEMM: 2 x (As[100][16]=1600 + Ws[16][128]=2048) = 7296 floats (29.2 KB).
    // Scan reuses the region as Cs[50][132] (6600 floats).
    __shared__ __align__(16) float smem[7296];
    float* As0 = smem;            // [100][16] linear
    float* Ws0 = smem + 1600;     // [16][128] linear
    float* As1 = smem + 3648;
    float* Ws1 = smem + 5248;

    const int tid = threadIdx.x;
    const int tg  = tid >> 4;    // 0..15 -> t = i*16 + tg
    const int ug  = tid & 15;    // 0..15 -> u cols {4ug..} and {64+4ug..}
    const int u0  = blockIdx.x * UN;
    const int b   = blockIdx.y;

    float acc[7][8];
    #pragma unroll
    for (int i = 0; i < 7; i++)
        #pragma unroll
        for (int j = 0; j < 8; j++) acc[i][j] = 0.f;

    const float* xb = x + (size_t)b * T * F;

    // A staging (verified since v2): 100 rows x 64 B = 400 slots; slot s ->
    // row s>>2, byte (s&3)*16; LDS dest = slot*16.
    const float* ga0 = xb + (size_t)(tid >> 2) * F + (tid & 3) * 4;
    const float* ga1 = xb + (size_t)(64 + (tid >> 2)) * F + (tid & 3) * 4;
    const int la0 = tid * 4;
    const int la1 = (256 + tid) * 4;
    const bool a1on = (tid < 144);           // slots 256..399
    const bool w0   = (tid < 64);            // wave 0 owns tail rows 96..99

    // W staging (verified v5): slot tid -> row tid>>5, col (tid&31)*4;
    // rows +8 at slot 256+tid.
    const float* gw0 = W + (size_t)(tid >> 5) * U + u0 + (tid & 31) * 4;
    const float* gw1 = W + (size_t)(8 + (tid >> 5)) * U + u0 + (tid & 31) * 4;
    const int lw0 = tid * 4;
    const int lw1 = (256 + tid) * 4;

#define STAGE(abuf, wbuf, kof)                                     \
    do {                                                           \
        gload_lds16(ga0 + (kof), (abuf) + la0);                    \
        if (a1on) gload_lds16(ga1 + (kof), (abuf) + la1);          \
        gload_lds16(gw0 + (size_t)(kof) * U, (wbuf) + lw0);        \
        gload_lds16(gw1 + (size_t)(kof) * U, (wbuf) + lw1);        \
    } while (0)

    // v5's exact per-row FMA order for a k-pair (W0,W1 = k's u-halves,
    // W2,W3 = (k+1)'s u-halves).
#define FMAROW(i, A, W0, W1, W2, W3)                                        \
    do {                                                                    \
        acc[i][0] += A.x * W0.x;  acc[i][1] += A.x * W0.y;                  \
        acc[i][2] += A.x * W0.z;  acc[i][3] += A.x * W0.w;                  \
        acc[i][4] += A.x * W1.x;  acc[i][5] += A.x * W1.y;                  \
        acc[i][6] += A.x * W1.z;  acc[i][7] += A.x * W1.w;                  \
        acc[i][0] += A.y * W2.x;  acc[i][1] += A.y * W2.y;                  \
        acc[i][2] += A.y * W2.z;  acc[i][3] += A.y * W2.w;                  \
        acc[i][4] += A.y * W3.x;  acc[i][5] += A.y * W3.y;                  \
        acc[i][6] += A.y * W3.z;  acc[i][7] += A.y * W3.w;                  \
    } while (0)

#define LOADA(dst0,dst1,dst2,dst3,dst4,dst5,dst6, koff)                     \
    do {                                                                    \
        dst0 = *(const float2*)(ap + 0 * 256 + (koff));                     \
        dst1 = *(const float2*)(ap + 1 * 256 + (koff));                     \
        dst2 = *(const float2*)(ap + 2 * 256 + (koff));                     \
        dst3 = *(const float2*)(ap + 3 * 256 + (koff));                     \
        dst4 = *(const float2*)(ap + 4 * 256 + (koff));                     \
        dst5 = *(const float2*)(ap + 5 * 256 + (koff));                     \
        if (w0) dst6 = *(const float2*)(ap + 6 * 256 + (koff));             \
    } while (0)

#define LOADW(d0,d1,d2,d3, koff)                                            \
    do {                                                                    \
        d0 = *(const float4*)(wp + (koff) * 128);                           \
        d1 = *(const float4*)(wp + (koff) * 128 + 64);                      \
        d2 = *(const float4*)(wp + ((koff) + 1) * 128);                     \
        d3 = *(const float4*)(wp + ((koff) + 1) * 128 + 64);                \
    } while (0)

#define FMASET(A0,A1,A2,A3,A4,A5,A6, W0,W1,W2,W3)                           \
    do {                                                                    \
        FMAROW(0, A0, W0, W1, W2, W3);                                      \
        FMAROW(1, A1, W0, W1, W2, W3);                                      \
        FMAROW(2, A2, W0, W1, W2, W3);                                      \
        FMAROW(3, A3, W0, W1, W2, W3);                                      \
        FMAROW(4, A4, W0, W1, W2, W3);                                      \
        FMAROW(5, A5, W0, W1, W2, W3);                                      \
        if (w0) { FMAROW(6, A6, W0, W1, W2, W3); }                          \
    } while (0)

    // Ping-pong over k-pairs: FMA blocks consume only preloaded registers.
#define COMPUTE(abuf, wbuf)                                                 \
    do {                                                                    \
        const float* ap = (abuf) + tg * 16;                                 \
        const float* wp = (wbuf) + ug * 4;                                  \
        float2 cA0,cA1,cA2,cA3,cA4,cA5,cA6, nA0,nA1,nA2,nA3,nA4,nA5,nA6;    \
        float4 cW0,cW1,cW2,cW3, nW0,nW1,nW2,nW3;                            \
        LOADA(cA0,cA1,cA2,cA3,cA4,cA5,cA6, 0);                              \
        LOADW(cW0,cW1,cW2,cW3, 0);                                          \
        _Pragma("unroll 1")                                                 \
        for (int kk = 0; kk < BK; kk += 4) {                                \
            LOADA(nA0,nA1,nA2,nA3,nA4,nA5,nA6, kk + 2);                     \
            LOADW(nW0,nW1,nW2,nW3, kk + 2);                                 \
            FMASET(cA0,cA1,cA2,cA3,cA4,cA5,cA6, cW0,cW1,cW2,cW3);           \
            const int k4 = (kk + 4) & 15;   /* 16 -> 0 dummy, discarded */  \
            LOADA(cA0,cA1,cA2,cA3,cA4,cA5,cA6, k4);                         \
            LOADW(cW0,cW1,cW2,cW3, k4);                                     \
            FMASET(nA0,nA1,nA2,nA3,nA4,nA5,nA6, nW0,nW1,nW2,nW3);           \
        }                                                                   \
    } while (0)

    // prologue: fill buffer set 0
    STAGE(As0, Ws0, 0);
    __syncthreads();   // auto vmcnt(0): tile 0 visible

    #pragma unroll 1
    for (int k0 = 0; k0 < F; k0 += 2 * BK) {
        STAGE(As1, Ws1, k0 + BK);             // async: next tile
        COMPUTE(As0, Ws0);
        __syncthreads();                      // drains STAGE, readers done
        if (k0 + 2 * BK < F) STAGE(As0, Ws0, k0 + 2 * BK);
        COMPUTE(As1, Ws1);
        __syncthreads();
    }

#undef STAGE
#undef COMPUTE
#undef FMASET
#undef LOADA
#undef LOADW
#undef FMAROW

    // ---- bias ----
    float bb[8];
    {
        float4 bv0 = *(const float4*)(bias + u0 + 4 * ug);
        float4 bv1 = *(const float4*)(bias + u0 + 64 + 4 * ug);
        bb[0] = bv0.x; bb[1] = bv0.y; bb[2] = bv0.z; bb[3] = bv0.w;
        bb[4] = bv1.x; bb[5] = bv1.y; bb[6] = bv1.z; bb[7] = bv1.w;
    }

    // ---- chunked dump + LIF scan (2 x 50 t-rows) ----
    float v = 0.f, cnt = 0.f;
    float* sp = spikes + (size_t)b * T * U + u0 + tid;   // used when tid<UN

    #pragma unroll
    for (int c = 0; c < 2; c++) {
        #pragma unroll
        for (int i = 0; i < 7; i++) {
            const int t = i * 16 + tg;
            if (t >= c * CHUNK && t < c * CHUNK + CHUNK && t < TMAX) {
                const int r = t - c * CHUNK;
                float4 d0, d1;
                d0.x = acc[i][0] + bb[0]; d0.y = acc[i][1] + bb[1];
                d0.z = acc[i][2] + bb[2]; d0.w = acc[i][3] + bb[3];
                d1.x = acc[i][4] + bb[4]; d1.y = acc[i][5] + bb[5];
                d1.z = acc[i][6] + bb[6]; d1.w = acc[i][7] + bb[7];
                *(float4*)(smem + r * CS + 4 * ug)      = d0;
                *(float4*)(smem + r * CS + 64 + 4 * ug) = d1;
            }
        }
        __syncthreads();
        if (tid < UN) {
#pragma clang fp contract(off)
            // rounding matches numpy elementwise exactly:
            // v = 0.25*v + round(0.75*c); spike = v > 1.0; v -= spike.
            for (int r = 0; r < CHUNK; r++) {
                float cval = smem[r * CS + tid];
                v = 0.25f * v + 0.75f * cval;
                float s = (v > 1.0f) ? 1.0f : 0.0f;
                v -= s;
                cnt += s;
                sp[(size_t)(c * CHUNK + r) * U] = s;
            }
        }
        __syncthreads();   // scan done before chunk 1 overwrites Cs
    }
    if (tid < UN) counts[(size_t)b * U + u0 + tid] = cnt;
}

extern "C" void kernel_launch(void* const* d_in, const int* in_sizes, int n_in,
                              void* d_out, int out_size, void* d_ws, size_t ws_size,
                              hipStream_t stream) {
    const float* x    = (const float*)d_in[0];  // [B,T,F]
    const float* kern = (const float*)d_in[1];  // [F,U]
    const float* bias = (const float*)d_in[2];  // [U]
    float* out = (float*)d_out;

    const int U = in_sizes[2];                 // 1024
    const int F = in_sizes[1] / U;             // 1024
    const int R = in_sizes[0] / F;             // B*T = 25600
    const int B = out_size / U - R;            // 256
    const int T = R / B;                       // 100

    float* spikes = out;
    float* counts = out + (size_t)R * U;

    dim3 grid(U / UN, B);                      // (8, 256)
    fused_snn<<<grid, 256, 0, stream>>>(x, kern, bias, spikes, counts,
                                        B, T, F, U);
}